// Round 1
// baseline (361.008 us; speedup 1.0000x reference)
//
#include <hip/hip_runtime.h>

#define DIMS 128
#define KNBR 64

__global__ __launch_bounds__(256) void penalty_kernel(
    const float* __restrict__ P,
    const int*   __restrict__ iIdx,
    const int*   __restrict__ jIdx,
    const float* __restrict__ S,
    float*       __restrict__ out)
{
    const int b    = blockIdx.x;
    const int lane = threadIdx.x & 63;
    const int wave = threadIdx.x >> 6;

    const int i = iIdx[b];
    // lane l holds elements [2l, 2l+1] of a row: 64 lanes x 8 B = 512 B coalesced
    const float2 pi = *reinterpret_cast<const float2*>(P + (size_t)i * DIMS + lane * 2);

    float acc = 0.0f;
    #pragma unroll 4
    for (int k = wave; k < KNBR; k += 4) {
        const int j = jIdx[b * KNBR + k];
        const float2 pj = *reinterpret_cast<const float2*>(P + (size_t)j * DIMS + lane * 2);
        const float dx = pi.x - pj.x;
        const float dy = pi.y - pj.y;
        float sq = dx * dx + dy * dy;
        // wave64 butterfly reduction
        #pragma unroll
        for (int off = 32; off > 0; off >>= 1)
            sq += __shfl_xor(sq, off, 64);
        acc += sqrtf(sq) * S[b * KNBR + k];
    }

    __shared__ float partial[4];
    if (lane == 0) partial[wave] = acc;
    __syncthreads();
    if (threadIdx.x == 0) {
        atomicAdd(out, partial[0] + partial[1] + partial[2] + partial[3]);
    }
}

extern "C" void kernel_launch(void* const* d_in, const int* in_sizes, int n_in,
                              void* d_out, int out_size, void* d_ws, size_t ws_size,
                              hipStream_t stream) {
    const float* P    = (const float*)d_in[0];
    const int*   iIdx = (const int*)d_in[1];
    const int*   jIdx = (const int*)d_in[2];
    const float* S    = (const float*)d_in[3];
    float*       out  = (float*)d_out;

    const int B = in_sizes[1];   // 4096 batch rows

    // Harness re-poisons d_out to 0xAA before every timed launch — zero it.
    hipMemsetAsync(out, 0, sizeof(float) * out_size, stream);

    penalty_kernel<<<B, 256, 0, stream>>>(P, iIdx, jIdx, S, out);
}

// Round 2
// 320.920 us; speedup vs baseline: 1.1249x; 1.1249x over previous
//
#include <hip/hip_runtime.h>

#define DIMS 128
#define KNBR 64

// Kernel 1: one block per batch row b. 4 waves x 16 (b,k) pairs each.
// Lane l of a wave holds elements [2l, 2l+1] of a 128-float row
// (64 lanes x 8 B = one fully coalesced 512 B row read).
// Per-block partial sum -> ws[b] (plain store, no atomics).
__global__ __launch_bounds__(256) void penalty_partial_kernel(
    const float* __restrict__ P,
    const int*   __restrict__ iIdx,
    const int*   __restrict__ jIdx,
    const float* __restrict__ S,
    float*       __restrict__ ws)
{
    const int b    = blockIdx.x;
    const int lane = threadIdx.x & 63;
    const int wave = threadIdx.x >> 6;

    const int i = iIdx[b];
    const float2 pi = *reinterpret_cast<const float2*>(P + (size_t)i * DIMS + lane * 2);

    // Preload wave-uniform indices/weights (16 per wave) so all row gathers
    // can be issued back-to-back and stay in flight together.
    int   js[16];
    float ss[16];
    #pragma unroll
    for (int u = 0; u < 16; ++u) {
        const int k = wave + 4 * u;
        js[u] = jIdx[b * KNBR + k];
        ss[u] = S[b * KNBR + k];
    }

    float acc = 0.0f;
    #pragma unroll
    for (int u = 0; u < 16; ++u) {
        const float2 pj = *reinterpret_cast<const float2*>(P + (size_t)js[u] * DIMS + lane * 2);
        const float dx = pi.x - pj.x;
        const float dy = pi.y - pj.y;
        float sq = dx * dx + dy * dy;
        #pragma unroll
        for (int off = 32; off > 0; off >>= 1)
            sq += __shfl_xor(sq, off, 64);
        acc += sqrtf(sq) * ss[u];
    }

    __shared__ float partial[4];
    if (lane == 0) partial[wave] = acc;
    __syncthreads();
    if (threadIdx.x == 0)
        ws[b] = partial[0] + partial[1] + partial[2] + partial[3];
}

// Kernel 2: single block reduces B partials -> out (plain store).
__global__ __launch_bounds__(256) void reduce_kernel(
    const float* __restrict__ ws, float* __restrict__ out, int n)
{
    const int t = threadIdx.x;
    float acc = 0.0f;
    for (int idx = t; idx < n; idx += 256)
        acc += ws[idx];

    #pragma unroll
    for (int off = 32; off > 0; off >>= 1)
        acc += __shfl_xor(acc, off, 64);

    __shared__ float partial[4];
    if ((t & 63) == 0) partial[t >> 6] = acc;
    __syncthreads();
    if (t == 0)
        out[0] = partial[0] + partial[1] + partial[2] + partial[3];
}

extern "C" void kernel_launch(void* const* d_in, const int* in_sizes, int n_in,
                              void* d_out, int out_size, void* d_ws, size_t ws_size,
                              hipStream_t stream) {
    const float* P    = (const float*)d_in[0];
    const int*   iIdx = (const int*)d_in[1];
    const int*   jIdx = (const int*)d_in[2];
    const float* S    = (const float*)d_in[3];
    float*       out  = (float*)d_out;
    float*       ws   = (float*)d_ws;

    const int B = in_sizes[1];   // 4096 batch rows

    penalty_partial_kernel<<<B, 256, 0, stream>>>(P, iIdx, jIdx, S, ws);
    reduce_kernel<<<1, 256, 0, stream>>>(ws, out, B);
}

// Round 3
// 319.010 us; speedup vs baseline: 1.1317x; 1.0060x over previous
//
#include <hip/hip_runtime.h>

#define DIMS 128
#define KNBR 64

// One block per batch row b (4096 blocks x 256 threads = 4 waves).
// Each wave handles 16 pairs as 4 groups of 4; within a group, a 16-lane
// team owns one pair: lane (sub= lane>>4, t = lane&15) reads 8 floats of the
// row as two float4s (offsets t*4 and 64+t*4). Each load instruction covers
// 4 rows x 256 B contiguous segments -> fully coalesced.
// Reduction: 4-step shfl_xor butterfly within the 16-lane team (vs 6-step
// full-wave), one sqrt per 4 pairs, wave total = sum(acc)/16 exactly.
__global__ __launch_bounds__(256) void penalty_partial_kernel(
    const float* __restrict__ P,
    const int*   __restrict__ iIdx,
    const int*   __restrict__ jIdx,
    const float* __restrict__ S,
    float*       __restrict__ ws)
{
    const int b    = blockIdx.x;
    const int lane = threadIdx.x & 63;
    const int wave = threadIdx.x >> 6;
    const int sub  = lane >> 4;    // pair within group (0..3)
    const int t    = lane & 15;    // position within 16-lane team

    const float* Pi = P + (size_t)iIdx[b] * DIMS;
    const float4 pi0 = *reinterpret_cast<const float4*>(Pi + t * 4);
    const float4 pi1 = *reinterpret_cast<const float4*>(Pi + 64 + t * 4);

    // pairs: k = wave*16 + g*4 + sub, g = 0..3
    const int kbase = b * KNBR + wave * 16 + sub;
    int   js[4];
    float sv[4];
    #pragma unroll
    for (int g = 0; g < 4; ++g) {
        js[g] = jIdx[kbase + g * 4];
        sv[g] = S[kbase + g * 4];
    }

    // Issue all 8 row gathers up front (8-deep memory-level parallelism).
    float4 pj0[4], pj1[4];
    #pragma unroll
    for (int g = 0; g < 4; ++g) {
        const float* Pj = P + (size_t)js[g] * DIMS;
        pj0[g] = *reinterpret_cast<const float4*>(Pj + t * 4);
        pj1[g] = *reinterpret_cast<const float4*>(Pj + 64 + t * 4);
    }

    float acc = 0.0f;
    #pragma unroll
    for (int g = 0; g < 4; ++g) {
        float d0 = pi0.x - pj0[g].x;
        float d1 = pi0.y - pj0[g].y;
        float d2 = pi0.z - pj0[g].z;
        float d3 = pi0.w - pj0[g].w;
        float d4 = pi1.x - pj1[g].x;
        float d5 = pi1.y - pj1[g].y;
        float d6 = pi1.z - pj1[g].z;
        float d7 = pi1.w - pj1[g].w;
        float sq = d0*d0 + d1*d1 + d2*d2 + d3*d3
                 + d4*d4 + d5*d5 + d6*d6 + d7*d7;
        // 4-step butterfly within the 16-lane team (masks < 16 stay in-team)
        sq += __shfl_xor(sq, 1, 64);
        sq += __shfl_xor(sq, 2, 64);
        sq += __shfl_xor(sq, 4, 64);
        sq += __shfl_xor(sq, 8, 64);
        acc += sqrtf(sq) * sv[g];
    }

    // acc is replicated 16x per pair: full-wave sum / 16 is exact.
    #pragma unroll
    for (int off = 32; off > 0; off >>= 1)
        acc += __shfl_xor(acc, off, 64);

    __shared__ float partial[4];
    if (lane == 0) partial[wave] = acc * 0.0625f;
    __syncthreads();
    if (threadIdx.x == 0)
        ws[b] = partial[0] + partial[1] + partial[2] + partial[3];
}

// Single block reduces B partials -> out (plain store, no atomics).
__global__ __launch_bounds__(256) void reduce_kernel(
    const float* __restrict__ ws, float* __restrict__ out, int n)
{
    const int t = threadIdx.x;
    float acc = 0.0f;
    for (int idx = t; idx < n; idx += 256)
        acc += ws[idx];

    #pragma unroll
    for (int off = 32; off > 0; off >>= 1)
        acc += __shfl_xor(acc, off, 64);

    __shared__ float partial[4];
    if ((t & 63) == 0) partial[t >> 6] = acc;
    __syncthreads();
    if (t == 0)
        out[0] = partial[0] + partial[1] + partial[2] + partial[3];
}

extern "C" void kernel_launch(void* const* d_in, const int* in_sizes, int n_in,
                              void* d_out, int out_size, void* d_ws, size_t ws_size,
                              hipStream_t stream) {
    const float* P    = (const float*)d_in[0];
    const int*   iIdx = (const int*)d_in[1];
    const int*   jIdx = (const int*)d_in[2];
    const float* S    = (const float*)d_in[3];
    float*       out  = (float*)d_out;
    float*       ws   = (float*)d_ws;

    const int B = in_sizes[1];   // 4096 batch rows

    penalty_partial_kernel<<<B, 256, 0, stream>>>(P, iIdx, jIdx, S, ws);
    reduce_kernel<<<1, 256, 0, stream>>>(ws, out, B);
}